// Round 1
// baseline (885.554 us; speedup 1.0000x reference)
//
#include <hip/hip_runtime.h>
#include <math.h>

// DifferentiableRiskBudgeting: B=512, P=256. One block (256 thr) per batch.
// Thread (ti=tid>>2, tj=tid&3) owns rows 4ti..4ti+3 x cols 64tj..64tj+63.
//   Rows +0..2: fp32 VGPRs as <2 x float> pairs -> v_pk_fma_f32.
//   Row  +3: fp32 LDS slab, stride 272 + tj-stride 68 (conflict-free b128).
// R6: amdgpu_waves_per_eu(2,2) — LDS caps us at 2 blocks/CU anyway, so let
// the register allocator use the full 256 arch-VGPR budget. Without it the
// compiler targeted 4 waves/EU (128 regs) and spilled the 192-float sigma
// tile to AGPRs, paying v_accvgpr_read per FMA operand (~2.5x VALU inflation;
// VGPR_Count stuck at 128 in R3-R5 was the tell).
// One barrier per PGD iteration (wave-local w copies, double-buffered stage).
// R7: projection is the serial-latency hot spot (11 dependent eval rounds,
// each ~6-level DPP reduce + readlane). Replace Illinois-10+final with
// safeguarded NEWTON on the piecewise-linear f (f' = -count(0<v-tau<c),
// a second, independent DPP chain that overlaps the sum chain) + warm-start
// tau from the previous PGD iteration. 11 -> 7 serial evaluations/iter,
// Illinois bracket+halving kept as the fallback so worst-case convergence
// is unchanged; final tau is Newton-exact on the terminal linear segment.

#define PP    256
#define MAXW  0.1f
#define EPSF  1e-8f
#define NPGD  250
#define NPOW  20
#define NPROJ 7

#define R3S   272   // sigma row-3 slab stride (floats); 272 % 32 == 16
#define TJS   68    // tj stride inside slab row;        68 % 32 == 4
#define WRDS  72    // w-copy block stride (64 data + 8 stagger)
#define VCOPY 280   // per-wave w copy stride

typedef float v2 __attribute__((ext_vector_type(2)));
typedef float v4t __attribute__((ext_vector_type(4)));

template<int CTRL>
__device__ __forceinline__ float dpp_zero(float x) {
    return __int_as_float(__builtin_amdgcn_update_dpp(
        0, __float_as_int(x), CTRL, 0xF, 0xF, true));
}
template<int CTRL>
__device__ __forceinline__ float dpp_keep(float x) {
    int xi = __float_as_int(x);
    return __int_as_float(__builtin_amdgcn_update_dpp(xi, xi, CTRL, 0xF, 0xF, false));
}
__device__ __forceinline__ float rdlane63(float x) {
    return __int_as_float(__builtin_amdgcn_readlane(__float_as_int(x), 63));
}
__device__ __forceinline__ float wave_sum63(float s) {
    s += dpp_zero<0x111>(s);
    s += dpp_zero<0x112>(s);
    s += dpp_zero<0x114>(s);
    s += dpp_zero<0x118>(s);
    s += dpp_zero<0x142>(s);
    s += dpp_zero<0x143>(s);
    return s;
}
__device__ __forceinline__ float wave_min63(float m) {
    m = fminf(m, dpp_keep<0x111>(m));
    m = fminf(m, dpp_keep<0x112>(m));
    m = fminf(m, dpp_keep<0x114>(m));
    m = fminf(m, dpp_keep<0x118>(m));
    m = fminf(m, dpp_keep<0x142>(m));
    m = fminf(m, dpp_keep<0x143>(m));
    return m;
}
__device__ __forceinline__ float wave_max63(float m) {
    m = fmaxf(m, dpp_keep<0x111>(m));
    m = fmaxf(m, dpp_keep<0x112>(m));
    m = fmaxf(m, dpp_keep<0x114>(m));
    m = fmaxf(m, dpp_keep<0x118>(m));
    m = fmaxf(m, dpp_keep<0x142>(m));
    m = fmaxf(m, dpp_keep<0x143>(m));
    return m;
}

__global__ __launch_bounds__(256)
__attribute__((amdgpu_waves_per_eu(2, 2)))
void drb_kernel(const float* __restrict__ sigma,
                const float* __restrict__ beta,
                const float* __restrict__ wprev,
                const float* __restrict__ pl1,
                const float* __restrict__ pl2,
                float* __restrict__ out)
{
    const int b    = blockIdx.x;
    const int tid  = threadIdx.x;
    const int lane = tid & 63;
    const int wv   = tid >> 6;
    const int ti   = tid >> 2;   // 0..63
    const int tj   = tid & 3;    // 0..3

    __shared__ __align__(16) float sigR3[64 * R3S];   // 69632 B
    __shared__ __align__(16) float wcop[4 * VCOPY];   //  4480 B
    __shared__ __align__(16) float stage[2][256];     //  2048 B

    const float* Sb = sigma + (size_t)b * (PP * PP);

    // ---- stage sigma: rows +0..2 -> v2 VGPR pairs; row +3 -> LDS slab
    v2 s0[32], s1[32], s2[32];
    {
        const float* r0 = Sb + (4 * ti + 0) * PP + 64 * tj;
        const float* r1 = Sb + (4 * ti + 1) * PP + 64 * tj;
        const float* r2 = Sb + (4 * ti + 2) * PP + 64 * tj;
#pragma unroll
        for (int k = 0; k < 16; ++k) {
            v4t t0 = *(const v4t*)(r0 + 4 * k);
            v4t t1 = *(const v4t*)(r1 + 4 * k);
            v4t t2 = *(const v4t*)(r2 + 4 * k);
            s0[2*k]   = __builtin_shufflevector(t0, t0, 0, 1);
            s0[2*k+1] = __builtin_shufflevector(t0, t0, 2, 3);
            s1[2*k]   = __builtin_shufflevector(t1, t1, 0, 1);
            s1[2*k+1] = __builtin_shufflevector(t1, t1, 2, 3);
            s2[2*k]   = __builtin_shufflevector(t2, t2, 0, 1);
            s2[2*k+1] = __builtin_shufflevector(t2, t2, 2, 3);
        }
        const float* r3 = Sb + (4 * ti + 3) * PP + 64 * tj;
        float* d3 = sigR3 + ti * R3S + TJS * tj;
#pragma unroll
        for (int k = 0; k < 16; ++k)
            *(v4t*)(d3 + 4 * k) = *(const v4t*)(r3 + 4 * k);
        // row-3 slab is written and read by the SAME thread -> no barrier.
    }

    const float bt   = beta[b * PP + tid];
    const float wp   = wprev[b * PP + tid];
    const float lam1 = expf(pl1[0]);
    const float lam2 = expf(pl2[0]);

    float* wme = wcop + wv * VCOPY;                // my wave's full-vector copy
    const int wst = 4 * lane + 8 * (lane >> 4);    // staggered write slot
    const float* wrd = wme + WRDS * tj;            // matvec read base (72*tj)

    // y = Sigma * w (w from my wave's copy); returns y[row tid]
    auto matvec = [&]() -> float {
        v2 y0 = {0.f, 0.f}, y1 = {0.f, 0.f}, y2 = {0.f, 0.f}, y3 = {0.f, 0.f};
        const float* p3 = sigR3 + ti * R3S + TJS * tj;
#pragma unroll
        for (int k = 0; k < 16; ++k) {
            v4t wq = *(const v4t*)(wrd + 4 * k);
            v2 w01 = __builtin_shufflevector(wq, wq, 0, 1);
            v2 w23 = __builtin_shufflevector(wq, wq, 2, 3);
            y0 = __builtin_elementwise_fma(s0[2*k],   w01, y0);
            y0 = __builtin_elementwise_fma(s0[2*k+1], w23, y0);
            y1 = __builtin_elementwise_fma(s1[2*k],   w01, y1);
            y1 = __builtin_elementwise_fma(s1[2*k+1], w23, y1);
            y2 = __builtin_elementwise_fma(s2[2*k],   w01, y2);
            y2 = __builtin_elementwise_fma(s2[2*k+1], w23, y2);
            v4t q = *(const v4t*)(p3 + 4 * k);
            v2 q01 = __builtin_shufflevector(q, q, 0, 1);
            v2 q23 = __builtin_shufflevector(q, q, 2, 3);
            y3 = __builtin_elementwise_fma(q01, w01, y3);
            y3 = __builtin_elementwise_fma(q23, w23, y3);
        }
        float r0 = y0.x + y0.y, r1 = y1.x + y1.y;
        float r2 = y2.x + y2.y, r3 = y3.x + y3.y;
        r0 += dpp_zero<0x4E>(r0); r1 += dpp_zero<0x4E>(r1);
        r2 += dpp_zero<0x4E>(r2); r3 += dpp_zero<0x4E>(r3);
        r0 += dpp_zero<0xB1>(r0); r1 += dpp_zero<0xB1>(r1);
        r2 += dpp_zero<0xB1>(r2); r3 += dpp_zero<0xB1>(r3);
        float a01 = (tj & 1) ? r1 : r0;
        float a23 = (tj & 1) ? r3 : r2;
        return (tj & 2) ? a23 : a01;
    };

    // ---- power iteration: each wave's copy initialized to 1/16 (wave-local)
    {
        v4t c = {0.0625f, 0.0625f, 0.0625f, 0.0625f};
        *(v4t*)(wme + wst) = c;
    }

    float y_last = 0.f, a_last = 1.f;
#pragma unroll 1
    for (int pi = 0; pi < NPOW; ++pi) {
        float y = matvec();
        stage[pi & 1][tid] = y;
        __syncthreads();
        v4t u4 = *(const v4t*)(&stage[pi & 1][4 * lane]);
        float ss = fmaf(u4.x, u4.x, fmaf(u4.y, u4.y, fmaf(u4.z, u4.z, u4.w * u4.w)));
        float a  = 1.f / (sqrtf(rdlane63(wave_sum63(ss))) + EPSF);
        v4t n4 = {a * u4.x, a * u4.y, a * u4.z, a * u4.w};
        *(v4t*)(wme + wst) = n4;          // full normalized vector, my copy
        y_last = y; a_last = a;
    }

    // ---- lmax = v' S v ; step
    float stepf;
    {
        float ysv = matvec();
        float p   = (a_last * y_last) * ysv;
        stage[0][tid] = p;
        __syncthreads();
        v4t p4 = *(const v4t*)(&stage[0][4 * lane]);
        float lmax = rdlane63(wave_sum63((p4.x + p4.y) + (p4.z + p4.w)));
        stepf = 1.f / (2.f * lmax + 2.f * lam2 + 1e-6f);
        __syncthreads();   // everyone done with stage[0] before PGD reuses it
    }

    // ---- PGD init: w0 = 1/256 (wave-local full copy)
    float w_own = 1.f / 256.f;
    {
        v4t c = {1.f/256.f, 1.f/256.f, 1.f/256.f, 1.f/256.f};
        *(v4t*)(wme + wst) = c;
    }
    const float Ac = 1.f - 2.f * lam2 * stepf;
    const float Bc = -2.f * stepf;
    const float Cc = stepf * (bt - lam1 + 2.f * lam2 * wp);

    float tau_ws = 0.f;   // warm-start tau carried across PGD iterations

#pragma unroll 1
    for (int it = 0; it < NPGD; ++it) {
        float y = matvec();
        float v_own = fmaf(w_own, Ac, fmaf(y, Bc, Cc));
        const int sb = it & 1;
        stage[sb][tid] = v_own;
        __syncthreads();                      // the ONLY barrier this iteration

        v4t v4 = *(const v4t*)(&stage[sb][4 * lane]);
        float mn = rdlane63(wave_min63(fminf(fminf(v4.x, v4.y), fminf(v4.z, v4.w))));
        float mx = rdlane63(wave_max63(fmaxf(fmaxf(v4.x, v4.y), fmaxf(v4.z, v4.w))));

        // Safeguarded Newton on f(tau)=s(tau)-1 (piecewise linear, monotone
        // decreasing). f' = -count(0 < v-tau < MAXW): a second wave-reduce
        // chain that is independent of the sum chain -> the two overlap.
        // Bracket bookkeeping is Illinois (halving of the stale endpoint) so
        // the fallback secant cannot stagnate. Known bracket values:
        //   f(mn-MAXW)=256*MAXW-1 (>0),  f(mx)=-1 (<0)
        float lo = mn - MAXW, flo = 256.f * MAXW - 1.f;
        float hi = mx,        fhi = -1.f;
        int side = 0;
        float tsec0 = (lo * fhi - hi * flo) * __builtin_amdgcn_rcpf(fhi - flo);
        bool ws_ok = (tau_ws > lo) & (tau_ws < hi);
        float tau = ws_ok ? tau_ws : tsec0;   // warm start from previous iter
#pragma unroll 1
        for (int r = 0; r < NPROJ; ++r) {
            float d0 = v4.x - tau, d1 = v4.y - tau;
            float d2 = v4.z - tau, d3 = v4.w - tau;
            float c0 = __builtin_amdgcn_fmed3f(d0, 0.f, MAXW);
            float c1 = __builtin_amdgcn_fmed3f(d1, 0.f, MAXW);
            float c2 = __builtin_amdgcn_fmed3f(d2, 0.f, MAXW);
            float c3 = __builtin_amdgcn_fmed3f(d3, 0.f, MAXW);
            float n0 = ((d0 > 0.f) & (d0 < MAXW)) ? 1.f : 0.f;
            float n1 = ((d1 > 0.f) & (d1 < MAXW)) ? 1.f : 0.f;
            float n2 = ((d2 > 0.f) & (d2 < MAXW)) ? 1.f : 0.f;
            float n3 = ((d3 > 0.f) & (d3 < MAXW)) ? 1.f : 0.f;
            // two independent reduce chains -> issue-interleaved by scheduler
            float S = wave_sum63((c0 + c1) + (c2 + c3));
            float N = wave_sum63((n0 + n1) + (n2 + n3));
            float f   = rdlane63(S) - 1.f;
            float cnt = rdlane63(N);
            bool pos = f > 0.f;
            float nflo = pos ? f   : ((side < 0) ? 0.5f * flo : flo);
            float nfhi = pos ? ((side > 0) ? 0.5f * fhi : fhi) : f;
            lo  = pos ? tau : lo;
            hi  = pos ? hi  : tau;
            flo = nflo; fhi = nfhi;
            side = pos ? 1 : -1;
            // Newton step (exact root of the current linear segment); fall
            // back to Illinois secant when out-of-bracket / cnt==0 / NaN.
            float tn = fmaf(f, __builtin_amdgcn_rcpf(cnt), tau);
            float ts = (lo * fhi - hi * flo) * __builtin_amdgcn_rcpf(fhi - flo);
            bool good = (tn > lo) & (tn < hi);
            tau = good ? tn : ts;
        }
        tau_ws = tau;

        v4t w4 = {__builtin_amdgcn_fmed3f(v4.x - tau, 0.f, MAXW),
                  __builtin_amdgcn_fmed3f(v4.y - tau, 0.f, MAXW),
                  __builtin_amdgcn_fmed3f(v4.z - tau, 0.f, MAXW),
                  __builtin_amdgcn_fmed3f(v4.w - tau, 0.f, MAXW)};
        *(v4t*)(wme + wst) = w4;              // full projected w, my wave's copy
        w_own = __builtin_amdgcn_fmed3f(v_own - tau, 0.f, MAXW);
    }

    // ---- renormalize + store
    stage[0][tid] = w_own;
    __syncthreads();
    v4t w4 = *(const v4t*)(&stage[0][4 * lane]);
    float S = rdlane63(wave_sum63((w4.x + w4.y) + (w4.z + w4.w)));
    out[b * PP + tid] = w_own / (S + EPSF);
}

extern "C" void kernel_launch(void* const* d_in, const int* in_sizes, int n_in,
                              void* d_out, int out_size, void* d_ws, size_t ws_size,
                              hipStream_t stream) {
    const float* sigma  = (const float*)d_in[0];
    const float* beta   = (const float*)d_in[1];
    const float* wprevp = (const float*)d_in[2];
    const float* pl1    = (const float*)d_in[3];
    const float* pl2    = (const float*)d_in[4];
    float* outp = (float*)d_out;
    drb_kernel<<<dim3(512), dim3(256), 0, stream>>>(sigma, beta, wprevp, pl1, pl2, outp);
}

// Round 2
// 586.376 us; speedup vs baseline: 1.5102x; 1.5102x over previous
//
#include <hip/hip_runtime.h>
#include <math.h>

// DifferentiableRiskBudgeting: B=512, P=256. One block (256 thr) per batch.
// Thread (ti=tid>>2, tj=tid&3) owns rows 4ti..4ti+3 x cols 64tj..64tj+63.
//   Rows +0..2: fp32 VGPRs as <2 x float> pairs -> v_pk_fma_f32.
//   Row  +3: fp32 LDS slab, stride 272 + tj-stride 68 (conflict-free b128).
// R6: amdgpu_waves_per_eu(2,2) — LDS caps us at 2 blocks/CU anyway; full 256
// arch-VGPR budget for the 192-float resident sigma tile.
// One barrier per PGD iteration (wave-local w copies, double-buffered stage).
// R7 (FAILED, +4%): fixed-7 Newton rounds w/ 2 DPP chains each — chains did
// not overlap; paid ~14 chain-latencies vs Illinois-11's 11.
// R8: warm-started safeguarded Newton with EARLY EXIT at |f|<=4e-6 (uniform
// scalar branch; all waves compute bit-identical f so no divergence). Warm
// tau is always bracket-safe (monotone f: an outside probe only widens the
// bracket with correct signs). Typical late-PGD cost: minmax + 1-3 fat
// rounds instead of minmax + 11 thin rounds; worst case capped at 10 rounds
// (>= R6 accuracy). Exit tol 4e-6 sits above fp32 sum noise (~1e-6) and
// gives tau error ~1e-7 << absmax 2.4e-4; final output renormalizes anyway.

#define PP    256
#define MAXW  0.1f
#define EPSF  1e-8f
#define NPGD  250
#define NPOW  20
#define NILLMAX 10
#define FTOL  4e-6f

#define R3S   272   // sigma row-3 slab stride (floats); 272 % 32 == 16
#define TJS   68    // tj stride inside slab row;        68 % 32 == 4
#define WRDS  72    // w-copy block stride (64 data + 8 stagger)
#define VCOPY 280   // per-wave w copy stride

typedef float v2 __attribute__((ext_vector_type(2)));
typedef float v4t __attribute__((ext_vector_type(4)));

template<int CTRL>
__device__ __forceinline__ float dpp_zero(float x) {
    return __int_as_float(__builtin_amdgcn_update_dpp(
        0, __float_as_int(x), CTRL, 0xF, 0xF, true));
}
template<int CTRL>
__device__ __forceinline__ float dpp_keep(float x) {
    int xi = __float_as_int(x);
    return __int_as_float(__builtin_amdgcn_update_dpp(xi, xi, CTRL, 0xF, 0xF, false));
}
__device__ __forceinline__ float rdlane63(float x) {
    return __int_as_float(__builtin_amdgcn_readlane(__float_as_int(x), 63));
}
__device__ __forceinline__ float wave_sum63(float s) {
    s += dpp_zero<0x111>(s);
    s += dpp_zero<0x112>(s);
    s += dpp_zero<0x114>(s);
    s += dpp_zero<0x118>(s);
    s += dpp_zero<0x142>(s);
    s += dpp_zero<0x143>(s);
    return s;
}
__device__ __forceinline__ float wave_min63(float m) {
    m = fminf(m, dpp_keep<0x111>(m));
    m = fminf(m, dpp_keep<0x112>(m));
    m = fminf(m, dpp_keep<0x114>(m));
    m = fminf(m, dpp_keep<0x118>(m));
    m = fminf(m, dpp_keep<0x142>(m));
    m = fminf(m, dpp_keep<0x143>(m));
    return m;
}
__device__ __forceinline__ float wave_max63(float m) {
    m = fmaxf(m, dpp_keep<0x111>(m));
    m = fmaxf(m, dpp_keep<0x112>(m));
    m = fmaxf(m, dpp_keep<0x114>(m));
    m = fmaxf(m, dpp_keep<0x118>(m));
    m = fmaxf(m, dpp_keep<0x142>(m));
    m = fmaxf(m, dpp_keep<0x143>(m));
    return m;
}

__global__ __launch_bounds__(256)
__attribute__((amdgpu_waves_per_eu(2, 2)))
void drb_kernel(const float* __restrict__ sigma,
                const float* __restrict__ beta,
                const float* __restrict__ wprev,
                const float* __restrict__ pl1,
                const float* __restrict__ pl2,
                float* __restrict__ out)
{
    const int b    = blockIdx.x;
    const int tid  = threadIdx.x;
    const int lane = tid & 63;
    const int wv   = tid >> 6;
    const int ti   = tid >> 2;   // 0..63
    const int tj   = tid & 3;    // 0..3

    __shared__ __align__(16) float sigR3[64 * R3S];   // 69632 B
    __shared__ __align__(16) float wcop[4 * VCOPY];   //  4480 B
    __shared__ __align__(16) float stage[2][256];     //  2048 B

    const float* Sb = sigma + (size_t)b * (PP * PP);

    // ---- stage sigma: rows +0..2 -> v2 VGPR pairs; row +3 -> LDS slab
    v2 s0[32], s1[32], s2[32];
    {
        const float* r0 = Sb + (4 * ti + 0) * PP + 64 * tj;
        const float* r1 = Sb + (4 * ti + 1) * PP + 64 * tj;
        const float* r2 = Sb + (4 * ti + 2) * PP + 64 * tj;
#pragma unroll
        for (int k = 0; k < 16; ++k) {
            v4t t0 = *(const v4t*)(r0 + 4 * k);
            v4t t1 = *(const v4t*)(r1 + 4 * k);
            v4t t2 = *(const v4t*)(r2 + 4 * k);
            s0[2*k]   = __builtin_shufflevector(t0, t0, 0, 1);
            s0[2*k+1] = __builtin_shufflevector(t0, t0, 2, 3);
            s1[2*k]   = __builtin_shufflevector(t1, t1, 0, 1);
            s1[2*k+1] = __builtin_shufflevector(t1, t1, 2, 3);
            s2[2*k]   = __builtin_shufflevector(t2, t2, 0, 1);
            s2[2*k+1] = __builtin_shufflevector(t2, t2, 2, 3);
        }
        const float* r3 = Sb + (4 * ti + 3) * PP + 64 * tj;
        float* d3 = sigR3 + ti * R3S + TJS * tj;
#pragma unroll
        for (int k = 0; k < 16; ++k)
            *(v4t*)(d3 + 4 * k) = *(const v4t*)(r3 + 4 * k);
        // row-3 slab is written and read by the SAME thread -> no barrier.
    }

    const float bt   = beta[b * PP + tid];
    const float wp   = wprev[b * PP + tid];
    const float lam1 = expf(pl1[0]);
    const float lam2 = expf(pl2[0]);

    float* wme = wcop + wv * VCOPY;                // my wave's full-vector copy
    const int wst = 4 * lane + 8 * (lane >> 4);    // staggered write slot
    const float* wrd = wme + WRDS * tj;            // matvec read base (72*tj)

    // y = Sigma * w (w from my wave's copy); returns y[row tid]
    auto matvec = [&]() -> float {
        v2 y0 = {0.f, 0.f}, y1 = {0.f, 0.f}, y2 = {0.f, 0.f}, y3 = {0.f, 0.f};
        const float* p3 = sigR3 + ti * R3S + TJS * tj;
#pragma unroll
        for (int k = 0; k < 16; ++k) {
            v4t wq = *(const v4t*)(wrd + 4 * k);
            v2 w01 = __builtin_shufflevector(wq, wq, 0, 1);
            v2 w23 = __builtin_shufflevector(wq, wq, 2, 3);
            y0 = __builtin_elementwise_fma(s0[2*k],   w01, y0);
            y0 = __builtin_elementwise_fma(s0[2*k+1], w23, y0);
            y1 = __builtin_elementwise_fma(s1[2*k],   w01, y1);
            y1 = __builtin_elementwise_fma(s1[2*k+1], w23, y1);
            y2 = __builtin_elementwise_fma(s2[2*k],   w01, y2);
            y2 = __builtin_elementwise_fma(s2[2*k+1], w23, y2);
            v4t q = *(const v4t*)(p3 + 4 * k);
            v2 q01 = __builtin_shufflevector(q, q, 0, 1);
            v2 q23 = __builtin_shufflevector(q, q, 2, 3);
            y3 = __builtin_elementwise_fma(q01, w01, y3);
            y3 = __builtin_elementwise_fma(q23, w23, y3);
        }
        float r0 = y0.x + y0.y, r1 = y1.x + y1.y;
        float r2 = y2.x + y2.y, r3 = y3.x + y3.y;
        r0 += dpp_zero<0x4E>(r0); r1 += dpp_zero<0x4E>(r1);
        r2 += dpp_zero<0x4E>(r2); r3 += dpp_zero<0x4E>(r3);
        r0 += dpp_zero<0xB1>(r0); r1 += dpp_zero<0xB1>(r1);
        r2 += dpp_zero<0xB1>(r2); r3 += dpp_zero<0xB1>(r3);
        float a01 = (tj & 1) ? r1 : r0;
        float a23 = (tj & 1) ? r3 : r2;
        return (tj & 2) ? a23 : a01;
    };

    // ---- power iteration: each wave's copy initialized to 1/16 (wave-local)
    {
        v4t c = {0.0625f, 0.0625f, 0.0625f, 0.0625f};
        *(v4t*)(wme + wst) = c;
    }

    float y_last = 0.f, a_last = 1.f;
#pragma unroll 1
    for (int pi = 0; pi < NPOW; ++pi) {
        float y = matvec();
        stage[pi & 1][tid] = y;
        __syncthreads();
        v4t u4 = *(const v4t*)(&stage[pi & 1][4 * lane]);
        float ss = fmaf(u4.x, u4.x, fmaf(u4.y, u4.y, fmaf(u4.z, u4.z, u4.w * u4.w)));
        float a  = 1.f / (sqrtf(rdlane63(wave_sum63(ss))) + EPSF);
        v4t n4 = {a * u4.x, a * u4.y, a * u4.z, a * u4.w};
        *(v4t*)(wme + wst) = n4;          // full normalized vector, my copy
        y_last = y; a_last = a;
    }

    // ---- lmax = v' S v ; step
    float stepf;
    {
        float ysv = matvec();
        float p   = (a_last * y_last) * ysv;
        stage[0][tid] = p;
        __syncthreads();
        v4t p4 = *(const v4t*)(&stage[0][4 * lane]);
        float lmax = rdlane63(wave_sum63((p4.x + p4.y) + (p4.z + p4.w)));
        stepf = 1.f / (2.f * lmax + 2.f * lam2 + 1e-6f);
        __syncthreads();   // everyone done with stage[0] before PGD reuses it
    }

    // ---- PGD init: w0 = 1/256 (wave-local full copy)
    float w_own = 1.f / 256.f;
    {
        v4t c = {1.f/256.f, 1.f/256.f, 1.f/256.f, 1.f/256.f};
        *(v4t*)(wme + wst) = c;
    }
    const float Ac = 1.f - 2.f * lam2 * stepf;
    const float Bc = -2.f * stepf;
    const float Cc = stepf * (bt - lam1 + 2.f * lam2 * wp);

    float tau_ws = 0.f;   // warm-start tau carried across PGD iterations

#pragma unroll 1
    for (int it = 0; it < NPGD; ++it) {
        float y = matvec();
        float v_own = fmaf(w_own, Ac, fmaf(y, Bc, Cc));
        const int sb = it & 1;
        stage[sb][tid] = v_own;
        __syncthreads();                      // the ONLY barrier this iteration

        v4t v4 = *(const v4t*)(&stage[sb][4 * lane]);
        float mn = rdlane63(wave_min63(fminf(fminf(v4.x, v4.y), fminf(v4.z, v4.w))));
        float mx = rdlane63(wave_max63(fmaxf(fmaxf(v4.x, v4.y), fmaxf(v4.z, v4.w))));

        // Warm-started safeguarded Newton on f(tau)=s(tau)-1 (piecewise
        // linear, monotone decreasing; f' = -count(0 < v-tau < MAXW)).
        // Early exit at |f|<=FTOL (uniform scalar branch, identical across
        // waves). Probe outside [lo,hi] only widens the bracket — signs stay
        // valid by monotonicity, so the warm start needs no validity check.
        // Known bracket values: f(mn-MAXW)=256*MAXW-1 (>0), f(mx)=-1 (<0).
        float lo = mn - MAXW, flo = 256.f * MAXW - 1.f;
        float hi = mx,        fhi = -1.f;
        int side = 0;
        float tau = tau_ws;
#pragma unroll 1
        for (int r = 0; r < NILLMAX; ++r) {
            float d0 = v4.x - tau, d1 = v4.y - tau;
            float d2 = v4.z - tau, d3 = v4.w - tau;
            float c0 = __builtin_amdgcn_fmed3f(d0, 0.f, MAXW);
            float c1 = __builtin_amdgcn_fmed3f(d1, 0.f, MAXW);
            float c2 = __builtin_amdgcn_fmed3f(d2, 0.f, MAXW);
            float c3 = __builtin_amdgcn_fmed3f(d3, 0.f, MAXW);
            float n0 = ((d0 > 0.f) & (d0 < MAXW)) ? 1.f : 0.f;
            float n1 = ((d1 > 0.f) & (d1 < MAXW)) ? 1.f : 0.f;
            float n2 = ((d2 > 0.f) & (d2 < MAXW)) ? 1.f : 0.f;
            float n3 = ((d3 > 0.f) & (d3 < MAXW)) ? 1.f : 0.f;
            float S = wave_sum63((c0 + c1) + (c2 + c3));
            float N = wave_sum63((n0 + n1) + (n2 + n3));
            float f   = rdlane63(S) - 1.f;
            float cnt = rdlane63(N);
            if (fabsf(f) <= FTOL) break;      // tau is final (uniform branch)
            bool pos = f > 0.f;
            float nflo = pos ? f   : ((side < 0) ? 0.5f * flo : flo);
            float nfhi = pos ? ((side > 0) ? 0.5f * fhi : fhi) : f;
            lo  = pos ? tau : lo;
            hi  = pos ? hi  : tau;
            flo = nflo; fhi = nfhi;
            side = pos ? 1 : -1;
            // Newton step (exact root of the current linear segment); fall
            // back to Illinois secant when out-of-bracket / cnt==0 / NaN.
            float tn = fmaf(f, __builtin_amdgcn_rcpf(cnt), tau);
            float ts = (lo * fhi - hi * flo) * __builtin_amdgcn_rcpf(fhi - flo);
            bool good = (tn > lo) & (tn < hi);
            tau = good ? tn : ts;
        }
        tau_ws = tau;

        v4t w4 = {__builtin_amdgcn_fmed3f(v4.x - tau, 0.f, MAXW),
                  __builtin_amdgcn_fmed3f(v4.y - tau, 0.f, MAXW),
                  __builtin_amdgcn_fmed3f(v4.z - tau, 0.f, MAXW),
                  __builtin_amdgcn_fmed3f(v4.w - tau, 0.f, MAXW)};
        *(v4t*)(wme + wst) = w4;              // full projected w, my wave's copy
        w_own = __builtin_amdgcn_fmed3f(v_own - tau, 0.f, MAXW);
    }

    // ---- renormalize + store
    stage[0][tid] = w_own;
    __syncthreads();
    v4t w4 = *(const v4t*)(&stage[0][4 * lane]);
    float S = rdlane63(wave_sum63((w4.x + w4.y) + (w4.z + w4.w)));
    out[b * PP + tid] = w_own / (S + EPSF);
}

extern "C" void kernel_launch(void* const* d_in, const int* in_sizes, int n_in,
                              void* d_out, int out_size, void* d_ws, size_t ws_size,
                              hipStream_t stream) {
    const float* sigma  = (const float*)d_in[0];
    const float* beta   = (const float*)d_in[1];
    const float* wprevp = (const float*)d_in[2];
    const float* pl1    = (const float*)d_in[3];
    const float* pl2    = (const float*)d_in[4];
    float* outp = (float*)d_out;
    drb_kernel<<<dim3(512), dim3(256), 0, stream>>>(sigma, beta, wprevp, pl1, pl2, outp);
}